// Round 3
// baseline (171.021 us; speedup 1.0000x reference)
//
#include <hip/hip_runtime.h>
#include <hip/hip_fp16.h>

#define EPS 1e-5f

typedef __attribute__((ext_vector_type(8))) _Float16 half8;
typedef __attribute__((ext_vector_type(4))) _Float16 half4;
typedef __attribute__((ext_vector_type(4))) float float4v;

__device__ __forceinline__ float rv_from(const float* sums2, int db)
{
    float s1 = 0.f, s2 = 0.f;
#pragma unroll
    for (int p = 0; p < 8; p++) {
        s1 += sums2[(db * 8 + p) * 2];
        s2 += sums2[(db * 8 + p) * 2 + 1];
    }
    const float inv = 1.f / 2097152.f;
    float mu = s1 * inv;
    float var = s2 * inv - mu * mu;
    return rsqrtf(var + EPS);
}

// ---------------------------------------------------------------------------
// convT (flat grid 304): one-shot conversions so every later kernel is fp16.
//  bid <256   : emb -> emb16 [b][t][c]  AND  embT16 [b][c][t]  (LDS transpose)
//  256..263   : WkT16 fp16 transpose
//  264..271   : Wo16[o][i] fp16
//  272..279   : Wv16 fp16 plain copy ([c][ch])
//  280..295   : GW/GQ partial Grams + wsum partials
//  296..303   : WqT16 hi/lo split-fp16 transpose  (WqT[i][c] = Wq[c][i])
// ---------------------------------------------------------------------------
__global__ __launch_bounds__(256)
void convT_k(const float* __restrict__ emb, const float* __restrict__ Wq,
             const float* __restrict__ Wk, const float* __restrict__ Wv,
             const float* __restrict__ Wo, __half* __restrict__ emb16,
             __half* __restrict__ embT16, __half* __restrict__ WkT16,
             __half* __restrict__ Wo16, __half* __restrict__ Wv16,
             float* __restrict__ GWQpart, float* __restrict__ wsp,
             __half* __restrict__ WqT16h, __half* __restrict__ WqT16l)
{
    __shared__ __align__(16) char smem[18432];
    const int tid = threadIdx.x;
    const int bid = blockIdx.x;

    if (bid < 256) {
        // emb conversion: block handles batch bb, tokens [t0, t0+128)
        __half (*T)[136] = (__half(*)[136])smem;   // [c][t] transposed tile
        const int bb = bid >> 4;
        const int t0 = (bid & 15) * 128;
        const float* src = emb + (long long)bb * 131072 + (long long)t0 * 64;
        __half* d16 = emb16 + (long long)bb * 131072 + (long long)t0 * 64;
#pragma unroll
        for (int it = 0; it < 8; it++) {
            int e = (tid + it * 256) * 4;
            int t = e >> 6, c = e & 63;
            float4 v = *(const float4*)(src + t * 64 + c);
            half4 h;
            h[0] = (_Float16)v.x; h[1] = (_Float16)v.y;
            h[2] = (_Float16)v.z; h[3] = (_Float16)v.w;
            *(half4*)(d16 + t * 64 + c) = h;
            T[c + 0][t] = (__half)h[0];
            T[c + 1][t] = (__half)h[1];
            T[c + 2][t] = (__half)h[2];
            T[c + 3][t] = (__half)h[3];
        }
        __syncthreads();
        __half* dT = embT16 + (long long)bb * 131072 + t0;
#pragma unroll
        for (int it = 0; it < 4; it++) {
            int e = (tid + it * 256) * 8;
            int c = e >> 7, tt = e & 127;
            *(half8*)(dT + (long long)c * 2048 + tt) = *(const half8*)&T[c][tt];
        }
    } else if (bid < 272) {
        float (*t)[65] = (float(*)[65])smem;
        const int which = (bid - 256) >> 3;      // 0 WkT16, 1 Wo16
        const int c0 = ((bid - 256) & 7) * 64;
        const int c = tid & 63, r4 = tid >> 6;
        if (which == 0) {
#pragma unroll
            for (int rr = r4; rr < 64; rr += 4)
                t[rr][c] = Wk[rr * 512 + c0 + c];
            __syncthreads();
#pragma unroll
            for (int rr = r4; rr < 64; rr += 4)
                WkT16[(c0 + rr) * 64 + c] = __float2half(t[c][rr]);
        } else {
#pragma unroll
            for (int rr = r4; rr < 64; rr += 4)
                t[rr][c] = Wo[(c0 + rr) * 64 + c];
            __syncthreads();
#pragma unroll
            for (int rr = r4; rr < 64; rr += 4)
                Wo16[rr * 512 + c0 + c] = __float2half(t[c][rr]);
        }
    } else if (bid < 280) {
        // Wv16 plain fp16 copy [c][ch]
        const int base = (bid - 272) * 4096;
#pragma unroll
        for (int it = 0; it < 4; it++) {
            int e = base + (tid + it * 256) * 4;
            float4 v = *(const float4*)(Wv + e);
            *(__half2*)(Wv16 + e)     = __floats2half2_rn(v.x, v.y);
            *(__half2*)(Wv16 + e + 2) = __floats2half2_rn(v.z, v.w);
        }
    } else if (bid < 296) {
        float (*Wl)[68] = (float(*)[68])smem;
        const int t2 = bid - 280;
        const int which = t2 >> 3;               // 0 -> Wk/GW, 1 -> Wq/GQ
        const int sl = t2 & 7;
        const int i0 = sl * 64;
        const float* W = which ? Wq : Wk;
        float* Gout = GWQpart + (long long)(which * 8 + sl) * 4096;
#pragma unroll
        for (int it = 0; it < 4; it++) {
            int e = tid + it * 256;
            int cc = e >> 4, i4 = (e & 15) * 4;
            *(float4*)&Wl[cc][i4] = *(const float4*)(W + cc * 512 + i0 + i4);
        }
        __syncthreads();
        if (tid < 64) {
            float s = 0.f;
#pragma unroll
            for (int j = 0; j < 64; j++) s += Wl[tid][j];
            wsp[(which * 8 + sl) * 64 + tid] = s;
        }
        const int cr = tid >> 2, cg = (tid & 3) * 16;
        float p[16] = {};
        for (int k = 0; k < 64; k++) {
            float a = Wl[cr][k];
#pragma unroll
            for (int j = 0; j < 16; j++) p[j] += a * Wl[cg + j][k];
        }
#pragma unroll
        for (int j = 0; j < 16; j++)
            Gout[cr * 64 + cg + j] = p[j];
    } else {
        // WqT split fp16: WqT[i][c] = Wq[c][i], hi + residual lo
        float (*t)[65] = (float(*)[65])smem;
        const int i0 = (bid - 296) * 64;
        const int c = tid & 63, r4 = tid >> 6;
#pragma unroll
        for (int rr = r4; rr < 64; rr += 4)
            t[rr][c] = Wq[rr * 512 + i0 + c];
        __syncthreads();
#pragma unroll
        for (int rr = r4; rr < 64; rr += 4) {
            float x = t[c][rr];
            __half h = __float2half(x);
            WqT16h[(i0 + rr) * 64 + c] = h;
            WqT16l[(i0 + rr) * 64 + c] = __float2half(x - __half2float(h));
        }
    }
}

// ---------------------------------------------------------------------------
// gram_k (grid 512): MFMA Gram partials from embT16, d=0 pairs only.
// Pure global-fragment MFMA: no LDS, no barriers, no conversion.
// ---------------------------------------------------------------------------
__global__ __launch_bounds__(256)
void gram_k(const __half* __restrict__ embT16, float* __restrict__ Gpart)
{
    const int tid = threadIdx.x, bid = blockIdx.x;
    const int ks = bid >> 6, z6 = bid & 63;
    const int b = z6 >> 3, bp = z6 & 7;
    const int lane = tid & 63, w = tid >> 6, q = lane >> 4, l16 = lane & 15;

    const __half* Arow = embT16 + (long long)b * 131072 +
                         (long long)(w * 16 + l16) * 2048 + ks * 256 + q * 8;
    const __half* Bbase = embT16 + 1048576 + (long long)bp * 131072 +
                          (long long)l16 * 2048 + ks * 256 + q * 8;

    float4v acc[4];
#pragma unroll
    for (int nt = 0; nt < 4; nt++) acc[nt] = (float4v)0.f;

#pragma unroll
    for (int t0 = 0; t0 < 256; t0 += 32) {
        half8 af = *(const half8*)(Arow + t0);
        half8 bf[4];
#pragma unroll
        for (int nt = 0; nt < 4; nt++)
            bf[nt] = *(const half8*)(Bbase + nt * 32768 + t0);
#pragma unroll
        for (int nt = 0; nt < 4; nt++)
            acc[nt] = __builtin_amdgcn_mfma_f32_16x16x32_f16(af, bf[nt], acc[nt], 0, 0, 0);
    }

    float* Gz = Gpart + (long long)ks * 262144 + (long long)z6 * 4096;
#pragma unroll
    for (int nt = 0; nt < 4; nt++)
#pragma unroll
        for (int t = 0; t < 4; t++) {
            int m = w * 16 + q * 4 + t;
            Gz[m * 64 + nt * 16 + l16] = acc[nt][t];
        }
}

// ---------------------------------------------------------------------------
// stats2: reduce Gpart (d=0 base, transpose for d=1), write logical G as
// TRANSPOSED split-fp16 (GT[c'][c], hi+lo), reduce GW/GQ/wsum, analytic IN
// stats -> sums2. grid 128 pairs.
// ---------------------------------------------------------------------------
__global__ __launch_bounds__(256)
void stats2_k(const float* __restrict__ Gpart, const float* __restrict__ GWQpart,
              const float* __restrict__ wsp, __half* __restrict__ GT16h,
              __half* __restrict__ GT16l, float* __restrict__ sums2)
{
    __shared__ float Graw[64][68], Gs[64][68], GQs[64][68], GWs[64][68];
    __shared__ float wqsS[64], wksS[64];
    const int tid = threadIdx.x;
    const int z = blockIdx.x;
    const int d = z >> 6, b = (z >> 3) & 7, bp = z & 7;
    const int zm = d ? (bp * 8 + b) : (b * 8 + bp);

    for (int f = tid * 4; f < 4096; f += 1024) {
        float4 g = make_float4(0.f, 0.f, 0.f, 0.f);
        float4 gw = g, gq = g;
#pragma unroll
        for (int s = 0; s < 8; s++) {
            float4 p = *(const float4*)(Gpart + (long long)s * 262144 + (long long)zm * 4096 + f);
            g.x += p.x; g.y += p.y; g.z += p.z; g.w += p.w;
            float4 w1 = *(const float4*)(GWQpart + (long long)s * 4096 + f);
            gw.x += w1.x; gw.y += w1.y; gw.z += w1.z; gw.w += w1.w;
            float4 q1 = *(const float4*)(GWQpart + (long long)(8 + s) * 4096 + f);
            gq.x += q1.x; gq.y += q1.y; gq.z += q1.z; gq.w += q1.w;
        }
        int rr = f >> 6, cc = f & 63;
        *(float4*)&Graw[rr][cc] = g;
        *(float4*)&GWs[rr][cc] = gw;
        *(float4*)&GQs[rr][cc] = gq;
    }
    if (tid < 64) {
        float a = 0.f, bsum = 0.f;
#pragma unroll
        for (int s = 0; s < 8; s++) {
            bsum += wsp[s * 64 + tid];          // Wk sums
            a    += wsp[(8 + s) * 64 + tid];    // Wq sums
        }
        wqsS[tid] = a; wksS[tid] = bsum;
    }
    __syncthreads();
    // logical G (transpose for d=1)
    for (int e = tid; e < 4096; e += 256) {
        int rr = e >> 6, cc = e & 63;
        Gs[rr][cc] = d ? Graw[cc][rr] : Graw[rr][cc];
    }
    __syncthreads();
    // store G TRANSPOSED as split fp16: GT[c'][c] = Gs[c][c']
    for (int e = tid; e < 4096; e += 256) {
        int cp = e >> 6, c = e & 63;
        float g = Gs[c][cp];
        __half h = __float2half(g);
        GT16h[(long long)z * 4096 + e] = h;
        GT16l[(long long)z * 4096 + e] = __float2half(g - __half2float(h));
    }

    const int r = tid >> 2;
    const int c0 = (tid & 3) * 16;
    float p1[16] = {}, p2[16] = {};
    for (int k = 0; k < 64; k++) {
        float gq = GQs[r][k], g = Gs[r][k];
#pragma unroll
        for (int j = 0; j < 16; j++) {
            p1[j] += gq * Gs[k][c0 + j];
            p2[j] += g  * GWs[k][c0 + j];
        }
    }
    float s2 = 0.f;
#pragma unroll
    for (int j = 0; j < 16; j++) s2 += p1[j] * p2[j];
    float s1 = 0.f;
    const float wq = wqsS[r];
#pragma unroll
    for (int j = 0; j < 16; j++) s1 += wq * Gs[r][c0 + j] * wksS[c0 + j];

    const int lane = tid & 63, w = tid >> 6;
#pragma unroll
    for (int off = 32; off; off >>= 1) {
        s1 += __shfl_down(s1, off, 64);
        s2 += __shfl_down(s2, off, 64);
    }
    __shared__ float r1[4], r2[4];
    if (lane == 0) { r1[w] = s1; r2[w] = s2; }
    __syncthreads();
    if (tid == 0) {
        sums2[z * 2]     = r1[0] + r1[1] + r1[2] + r1[3];
        sums2[z * 2 + 1] = r2[0] + r2[1] + r2[2] + r2[3];
    }
}

// ---------------------------------------------------------------------------
// Fused E + MS, BARRIER-FREE main loop.
// Key invariant: Es and Pt rows are wave-private (wave w owns rows
// [w*32, w*32+32)), so E->S and exp->M orderings are same-wave LDS
// dependencies handled by lgkmcnt -- no __syncthreads needed.
// Wk/Wv fragments are read directly from global (64 KB each, L2-resident
// across all 512 blocks); the old per-chunk LDS staging + 2 barriers/chunk
// are gone. Only the cross-wave Mt-transpose epilogue needs 2 barriers.
// grid (128 z, 4 it), block 256. LDS 36 KB.
// ---------------------------------------------------------------------------
__global__ __launch_bounds__(256)
void mfma_ms(const __half* __restrict__ WqT16h, const __half* __restrict__ WqT16l,
             const __half* __restrict__ GT16h, const __half* __restrict__ GT16l,
             const __half* __restrict__ WkT16, const __half* __restrict__ Wv16,
             const float* __restrict__ sums2, float* __restrict__ rsp,
             __half* __restrict__ Mt)
{
    __shared__ __half Es[128][72];
    __shared__ __half Pt[128][72];   // reused as MtS[64][144] at the end

    const int tid = threadIdx.x;
    const int z = blockIdx.x;
    const int it = blockIdx.y;
    const int db = z >> 3, bp = z & 7;
    const int i0base = it * 128;

    const int lane = tid & 63, w = tid >> 6, q = lane >> 4, l16 = lane & 15;
    const float rv = rv_from(sums2, db);

    // ---- E-phase: Es rows [w*32, w*32+32) from WqT (split) x GT (split) ----
    {
        const __half* Wh = WqT16h + (long long)i0base * 64;
        const __half* Wl = WqT16l + (long long)i0base * 64;
        const __half* Gh = GT16h + (long long)z * 4096;
        const __half* Gl = GT16l + (long long)z * 4096;
        float4v eacc[2][4];
#pragma unroll
        for (int a = 0; a < 2; a++)
#pragma unroll
            for (int b2 = 0; b2 < 4; b2++) eacc[a][b2] = (float4v)0.f;
#pragma unroll
        for (int kc = 0; kc < 64; kc += 32) {
            half8 ah[2], al[2], bh[4], bl[4];
#pragma unroll
            for (int mt = 0; mt < 2; mt++) {
                const int i = w * 32 + mt * 16 + l16;
                ah[mt] = *(const half8*)(Wh + i * 64 + kc + q * 8);
                al[mt] = *(const half8*)(Wl + i * 64 + kc + q * 8);
            }
#pragma unroll
            for (int nt = 0; nt < 4; nt++) {
                const int cp = nt * 16 + l16;
                bh[nt] = *(const half8*)(Gh + cp * 64 + kc + q * 8);
                bl[nt] = *(const half8*)(Gl + cp * 64 + kc + q * 8);
            }
#pragma unroll
            for (int mt = 0; mt < 2; mt++)
#pragma unroll
                for (int nt = 0; nt < 4; nt++) {
                    eacc[mt][nt] = __builtin_amdgcn_mfma_f32_16x16x32_f16(ah[mt], bh[nt], eacc[mt][nt], 0, 0, 0);
                    eacc[mt][nt] = __builtin_amdgcn_mfma_f32_16x16x32_f16(ah[mt], bl[nt], eacc[mt][nt], 0, 0, 0);
                    eacc[mt][nt] = __builtin_amdgcn_mfma_f32_16x16x32_f16(al[mt], bh[nt], eacc[mt][nt], 0, 0, 0);
                }
        }
#pragma unroll
        for (int mt = 0; mt < 2; mt++)
#pragma unroll
            for (int nt = 0; nt < 4; nt++)
#pragma unroll
                for (int t = 0; t < 4; t++)
                    Es[w * 32 + mt * 16 + q * 4 + t][nt * 16 + l16] =
                        __float2half(eacc[mt][nt][t]);
    }
    // No barrier: S-phase reads only this wave's Es rows.

    float4v macc[2][4];   // [mt2: i-group][nt2: c'-group]
#pragma unroll
    for (int a = 0; a < 2; a++)
#pragma unroll
        for (int b2 = 0; b2 < 4; b2++) macc[a][b2] = (float4v)0.f;
    float rsacc[2] = {0.f, 0.f};

    for (int ch0 = 0; ch0 < 512; ch0 += 64) {
        // S-mfma: m=ch (4 mt, fragments direct from global WkT16),
        //         n=i (2 nt per wave, from wave-private Es), k=c' (2 kc)
        float4v sacc[4][2];
#pragma unroll
        for (int a = 0; a < 4; a++)
#pragma unroll
            for (int b2 = 0; b2 < 2; b2++) sacc[a][b2] = (float4v)0.f;
#pragma unroll
        for (int kc = 0; kc < 64; kc += 32) {
            half8 af[4], bf[2];
#pragma unroll
            for (int mt = 0; mt < 4; mt++)
                af[mt] = *(const half8*)(WkT16 +
                    (long long)(ch0 + mt * 16 + l16) * 64 + kc + q * 8);
#pragma unroll
            for (int nt = 0; nt < 2; nt++)
                bf[nt] = *(const half8*)&Es[w * 32 + nt * 16 + l16][kc + q * 8];
#pragma unroll
            for (int mt = 0; mt < 4; mt++)
#pragma unroll
                for (int nt = 0; nt < 2; nt++)
                    sacc[mt][nt] = __builtin_amdgcn_mfma_f32_16x16x32_f16(af[mt], bf[nt], sacc[mt][nt], 0, 0, 0);
        }

        // exp -> Pt[i][ch] (wave-private rows) + rs accum
#pragma unroll
        for (int nt = 0; nt < 2; nt++) {
            const int i = w * 32 + nt * 16 + l16;
#pragma unroll
            for (int mt = 0; mt < 4; mt++) {
                float e0 = __expf(rv * sacc[mt][nt][0]);
                float e1 = __expf(rv * sacc[mt][nt][1]);
                float e2 = __expf(rv * sacc[mt][nt][2]);
                float e3 = __expf(rv * sacc[mt][nt][3]);
                rsacc[nt] += e0 + e1 + e2 + e3;
                const int ch = mt * 16 + q * 4;
                *(__half2*)&Pt[i][ch]     = __floats2half2_rn(e0, e1);
                *(__half2*)&Pt[i][ch + 2] = __floats2half2_rn(e2, e3);
            }
        }
        // No barrier: M-phase reads only this wave's Pt rows.

        // M-mfma: m=i (2 mt2, wave-private Pt), n=c' (4 nt2, fragments
        //         direct from global Wv16), k=ch (2 kc)
#pragma unroll
        for (int kc = 0; kc < 64; kc += 32) {
            half8 af2[2], bf2[4];
#pragma unroll
            for (int mt2 = 0; mt2 < 2; mt2++)
                af2[mt2] = *(const half8*)&Pt[w * 32 + mt2 * 16 + l16][kc + q * 8];
#pragma unroll
            for (int nt2 = 0; nt2 < 4; nt2++)
                bf2[nt2] = *(const half8*)(Wv16 +
                    (long long)(nt2 * 16 + l16) * 512 + ch0 + kc + q * 8);
#pragma unroll
            for (int mt2 = 0; mt2 < 2; mt2++)
#pragma unroll
                for (int nt2 = 0; nt2 < 4; nt2++)
                    macc[mt2][nt2] = __builtin_amdgcn_mfma_f32_16x16x32_f16(af2[mt2], bf2[nt2], macc[mt2][nt2], 0, 0, 0);
        }
    }

    // rs partials: reduce over q (lane bits 4,5), store per (i, bp)
#pragma unroll
    for (int nt = 0; nt < 2; nt++) {
        float p = rsacc[nt];
        p += __shfl_xor(p, 16, 64);
        p += __shfl_xor(p, 32, 64);
        if (q == 0)
            rsp[(long long)(db * 512 + i0base + w * 32 + nt * 16 + l16) * 8 + bp] = p;
    }
    __syncthreads();   // all waves done with their Pt rows before aliasing as MtS

    // Mt store: macc -> MtS[c'][i] (LDS) -> coalesced global [c'][i0base..+128]
    __half (*MtS)[144] = (__half(*)[144])&Pt[0][0];
    const float sc = 1.f / 4096.f;
#pragma unroll
    for (int mt2 = 0; mt2 < 2; mt2++)
#pragma unroll
        for (int nt2 = 0; nt2 < 4; nt2++) {
            const int cp = nt2 * 16 + l16;
            const int il = w * 32 + mt2 * 16 + q * 4;
#pragma unroll
            for (int t = 0; t < 4; t++)
                MtS[cp][il + t] = __float2half(macc[mt2][nt2][t] * sc);
        }
    __syncthreads();
    __half* Mz = Mt + (long long)z * 32768;
    {
        const int row = tid >> 2, seg = (tid & 3) * 32;
#pragma unroll
        for (int j = 0; j < 4; j++)
            *(half8*)(Mz + (long long)row * 512 + i0base + seg + j * 8) =
                *(const half8*)&MtS[row][seg + j * 8];
    }
}

// ---------------------------------------------------------------------------
// N gemm: NT[db][o][bp*64+c'] = sum_i Mt[z][c'][i]*(4096/rs[db][i])*Wo16[o][i]
// m=c', n=o (1 nt/wave), K=512. grid 128 (db*8+bp), block 256.
// ---------------------------------------------------------------------------
__global__ __launch_bounds__(256)
void mfma_n(const __half* __restrict__ Mt, const __half* __restrict__ Wo16,
            const float* __restrict__ rsp, __half* __restrict__ NT)
{
    __shared__ __half Mts[64][72];
    __shared__ __half Wos[64][72];
    __shared__ float invrS[64];
    const int tid = threadIdx.x;
    const int db = blockIdx.x >> 3, bp = blockIdx.x & 7;
    const __half* Mz = Mt + (long long)(db * 8 + bp) * 32768;
    const int lane = tid & 63, w = tid >> 6, q = lane >> 4, l16 = lane & 15;

    float4v acc[4];
#pragma unroll
    for (int mt = 0; mt < 4; mt++) acc[mt] = (float4v)0.f;

    const int srow = tid >> 2, sc8 = (tid & 3) * 16;

    for (int i0 = 0; i0 < 512; i0 += 64) {
        __syncthreads();
        if (tid < 64) {
            const float* rp = rsp + (long long)(db * 512 + i0 + tid) * 8;
            float4 a = *(const float4*)rp;
            float4 b = *(const float4*)(rp + 4);
            invrS[tid] = 4096.0f / (a.x + a.y + a.z + a.w + b.x + b.y + b.z + b.w);
        }
        __syncthreads();
#pragma unroll
        for (int h = 0; h < 2; h++) {
            half8 v = *(const half8*)(Mz + (long long)srow * 512 + i0 + sc8 + h * 8);
            half8 o;
#pragma unroll
            for (int j = 0; j < 8; j++)
                o[j] = (_Float16)((float)v[j] * invrS[sc8 + h * 8 + j]);
            *(half8*)&Mts[srow][sc8 + h * 8] = o;
            *(half8*)&Wos[srow][sc8 + h * 8] =
                *(const half8*)(Wo16 + (long long)srow * 512 + i0 + sc8 + h * 8);
        }
        __syncthreads();
#pragma unroll
        for (int kc = 0; kc < 64; kc += 32) {
            half8 af[4];
#pragma unroll
            for (int mt = 0; mt < 4; mt++)
                af[mt] = *(const half8*)&Mts[mt * 16 + l16][kc + q * 8];
            half8 bf = *(const half8*)&Wos[w * 16 + l16][kc + q * 8];
#pragma unroll
            for (int mt = 0; mt < 4; mt++)
                acc[mt] = __builtin_amdgcn_mfma_f32_16x16x32_f16(af[mt], bf, acc[mt], 0, 0, 0);
        }
    }

    __half* Nz = NT + (long long)db * 32768;
    const int o = w * 16 + l16;
#pragma unroll
    for (int mt = 0; mt < 4; mt++) {
        const int k = bp * 64 + mt * 16 + q * 4;
        *(__half2*)(Nz + (long long)o * 512 + k)     = __floats2half2_rn(acc[mt][0], acc[mt][1]);
        *(__half2*)(Nz + (long long)o * 512 + k + 2) = __floats2half2_rn(acc[mt][2], acc[mt][3]);
    }
}

// ---------------------------------------------------------------------------
// MFMA out:  out[db][n][o] = sum_{bp,c} emb16_kv[bp][n][c] * NT[db][o][bp*64+c]
// Direct global-fragment MFMA: no LDS, no barriers, no fp32->fp16 conversion.
// ---------------------------------------------------------------------------
__global__ __launch_bounds__(256)
void mfma_out(const __half* __restrict__ emb16, const __half* __restrict__ NT,
              float* __restrict__ out)
{
    const int tid = threadIdx.x;
    const int db = blockIdx.y;
    const int d = db >> 3;
    const int n0 = blockIdx.x * 128;
    const __half* Xb = emb16 + (long long)(1 - d) * 1048576;
    const __half* Bz = NT + (long long)db * 32768;

    const int lane = tid & 63, w = tid >> 6, q = lane >> 4, l16 = lane & 15;

    float4v acc[2][4];
#pragma unroll
    for (int a = 0; a < 2; a++)
#pragma unroll
        for (int b = 0; b < 4; b++) acc[a][b] = (float4v)0.f;

    for (int bp = 0; bp < 8; bp++) {
        const __half* src = Xb + (long long)bp * 131072 + (long long)n0 * 64;
#pragma unroll
        for (int kc = 0; kc < 64; kc += 32) {
            half8 af[2], bf[4];
#pragma unroll
            for (int mt = 0; mt < 2; mt++)
                af[mt] = *(const half8*)(src + (long long)(w * 32 + mt * 16 + l16) * 64 + kc + q * 8);
#pragma unroll
            for (int ot = 0; ot < 4; ot++)
                bf[ot] = *(const half8*)(Bz + (long long)(ot * 16 + l16) * 512 + bp * 64 + kc + q * 8);
#pragma unroll
            for (int mt = 0; mt < 2; mt++)
#pragma unroll
                for (int ot = 0; ot < 4; ot++)
                    acc[mt][ot] = __builtin_amdgcn_mfma_f32_16x16x32_f16(af[mt], bf[ot], acc[mt][ot], 0, 0, 0);
        }
    }

    float* Od = out + (long long)db * 131072;
#pragma unroll
    for (int mt = 0; mt < 2; mt++)
#pragma unroll
        for (int ot = 0; ot < 4; ot++)
#pragma unroll
            for (int t = 0; t < 4; t++) {
                int n = n0 + w * 32 + mt * 16 + q * 4 + t;
                Od[(long long)n * 64 + ot * 16 + l16] = acc[mt][ot][t];
            }
}

// ---------------------------------------------------------------------------
// Workspace (float offsets, no zero-init anywhere):
//   Gpart @0: 2097152
//   GWQpart @2097152: 65536 | wsp @2162688: 1024 | sums2 @2163712: 256
//   GT16h (half) @2163968: 524288 h -> 2426112
//   GT16l (half) @2426112: 524288 h -> 2688256
//   rsp @2688256: 65536 -> 2753792      ((db*512+i)*8 + bp)
//   WkT16 (half) @2753792 -> 2770176 | Wv16 @2770176 -> 2786560
//   Wo16 @2786560 -> 2802944
//   WqT16h @2802944 -> 2819328 | WqT16l @2819328 -> 2835712
//   Mt (half) @2835712: 4194304 h -> 4932864   ([z][c'][i])
//   NT (half) @4932864: 524288 h -> 5195008    ([db][o][k])
//   emb16 (half) @5195008: 2097152 h -> 6243584   ([b][t][c])
//   embT16 (half) @6243584: 2097152 h -> 7292160  ([b][c][t])
// ---------------------------------------------------------------------------
extern "C" void kernel_launch(void* const* d_in, const int* in_sizes, int n_in,
                              void* d_out, int out_size, void* d_ws, size_t ws_size,
                              hipStream_t stream)
{
    const float* emb = (const float*)d_in[0];
    const float* Wq  = (const float*)d_in[1];
    const float* Wk  = (const float*)d_in[2];
    const float* Wv  = (const float*)d_in[3];
    const float* Wo  = (const float*)d_in[4];
    float* out = (float*)d_out;
    float* ws  = (float*)d_ws;

    float* Gpart   = ws;
    float* GWQpart = ws + 2097152;
    float* wsp     = ws + 2162688;
    float* sums2   = ws + 2163712;
    __half* GT16h  = (__half*)(ws + 2163968);
    __half* GT16l  = (__half*)(ws + 2426112);
    float* rsp     = ws + 2688256;
    __half* WkT16  = (__half*)(ws + 2753792);
    __half* Wv16   = (__half*)(ws + 2770176);
    __half* Wo16   = (__half*)(ws + 2786560);
    __half* WqT16h = (__half*)(ws + 2802944);
    __half* WqT16l = (__half*)(ws + 2819328);
    __half* Mt     = (__half*)(ws + 2835712);
    __half* NT     = (__half*)(ws + 4932864);
    __half* emb16  = (__half*)(ws + 5195008);
    __half* embT16 = (__half*)(ws + 6243584);

    // one-shot fp16 conversions (emb both layouts) + weight prep + GW/GQ/wsum
    convT_k<<<304, 256, 0, stream>>>(emb, Wq, Wk, Wv, Wo, emb16, embT16,
                                     WkT16, Wo16, Wv16, GWQpart, wsp,
                                     WqT16h, WqT16l);

    // Gram partials (d=0 only), pure global-fragment MFMA
    gram_k<<<512, 256, 0, stream>>>(embT16, Gpart);

    // reduce partials (+transpose for d=1) + split-fp16 G^T + analytic stats
    stats2_k<<<128, 256, 0, stream>>>(Gpart, GWQpart, wsp, GT16h, GT16l, sums2);

    // fused E (split-fp16 MFMA) + S + exp + V-contraction, barrier-free loop
    mfma_ms<<<dim3(128, 4), 256, 0, stream>>>(WqT16h, WqT16l, GT16h, GT16l,
                                              WkT16, Wv16, sums2, rsp, Mt);

    // NT[db][o][k] = sum_i (Mt/rs) * Wo   (softmax normalization folded here)
    mfma_n<<<128, 256, 0, stream>>>(Mt, Wo16, rsp, NT);

    // out[db][n][o] = sum_k emb16_kv * NT   (MFMA f16, fp32 out)
    mfma_out<<<dim3(16, 16), 256, 0, stream>>>(emb16, NT, out);
}

// Round 4
// 156.463 us; speedup vs baseline: 1.0930x; 1.0930x over previous
//
#include <hip/hip_runtime.h>
#include <hip/hip_fp16.h>

#define EPS 1e-5f

typedef __attribute__((ext_vector_type(8))) _Float16 half8;
typedef __attribute__((ext_vector_type(4))) _Float16 half4;
typedef __attribute__((ext_vector_type(4))) float float4v;

__device__ __forceinline__ float rv_from(const float* sums2, int db)
{
    float s1 = 0.f, s2 = 0.f;
#pragma unroll
    for (int p = 0; p < 8; p++) {
        s1 += sums2[(db * 8 + p) * 2];
        s2 += sums2[(db * 8 + p) * 2 + 1];
    }
    const float inv = 1.f / 2097152.f;
    float mu = s1 * inv;
    float var = s2 * inv - mu * mu;
    return rsqrtf(var + EPS);
}

// ---------------------------------------------------------------------------
// convT (flat grid 304): one-shot conversions so every later kernel is fp16.
// ---------------------------------------------------------------------------
__global__ __launch_bounds__(256)
void convT_k(const float* __restrict__ emb, const float* __restrict__ Wq,
             const float* __restrict__ Wk, const float* __restrict__ Wv,
             const float* __restrict__ Wo, __half* __restrict__ emb16,
             __half* __restrict__ embT16, __half* __restrict__ WkT16,
             __half* __restrict__ Wo16, __half* __restrict__ Wv16,
             float* __restrict__ GWQpart, float* __restrict__ wsp,
             __half* __restrict__ WqT16h, __half* __restrict__ WqT16l)
{
    __shared__ __align__(16) char smem[18432];
    const int tid = threadIdx.x;
    const int bid = blockIdx.x;

    if (bid < 256) {
        // emb conversion: block handles batch bb, tokens [t0, t0+128)
        __half (*T)[136] = (__half(*)[136])smem;   // [c][t] transposed tile
        const int bb = bid >> 4;
        const int t0 = (bid & 15) * 128;
        const float* src = emb + (long long)bb * 131072 + (long long)t0 * 64;
        __half* d16 = emb16 + (long long)bb * 131072 + (long long)t0 * 64;
#pragma unroll
        for (int it = 0; it < 8; it++) {
            int e = (tid + it * 256) * 4;
            int t = e >> 6, c = e & 63;
            float4 v = *(const float4*)(src + t * 64 + c);
            half4 h;
            h[0] = (_Float16)v.x; h[1] = (_Float16)v.y;
            h[2] = (_Float16)v.z; h[3] = (_Float16)v.w;
            *(half4*)(d16 + t * 64 + c) = h;
            T[c + 0][t] = (__half)h[0];
            T[c + 1][t] = (__half)h[1];
            T[c + 2][t] = (__half)h[2];
            T[c + 3][t] = (__half)h[3];
        }
        __syncthreads();
        __half* dT = embT16 + (long long)bb * 131072 + t0;
#pragma unroll
        for (int it = 0; it < 4; it++) {
            int e = (tid + it * 256) * 8;
            int c = e >> 7, tt = e & 127;
            *(half8*)(dT + (long long)c * 2048 + tt) = *(const half8*)&T[c][tt];
        }
    } else if (bid < 272) {
        float (*t)[65] = (float(*)[65])smem;
        const int which = (bid - 256) >> 3;      // 0 WkT16, 1 Wo16
        const int c0 = ((bid - 256) & 7) * 64;
        const int c = tid & 63, r4 = tid >> 6;
        if (which == 0) {
#pragma unroll
            for (int rr = r4; rr < 64; rr += 4)
                t[rr][c] = Wk[rr * 512 + c0 + c];
            __syncthreads();
#pragma unroll
            for (int rr = r4; rr < 64; rr += 4)
                WkT16[(c0 + rr) * 64 + c] = __float2half(t[c][rr]);
        } else {
#pragma unroll
            for (int rr = r4; rr < 64; rr += 4)
                t[rr][c] = Wo[(c0 + rr) * 64 + c];
            __syncthreads();
#pragma unroll
            for (int rr = r4; rr < 64; rr += 4)
                Wo16[rr * 512 + c0 + c] = __float2half(t[c][rr]);
        }
    } else if (bid < 280) {
        // Wv16 plain fp16 copy [c][ch]
        const int base = (bid - 272) * 4096;
#pragma unroll
        for (int it = 0; it < 4; it++) {
            int e = base + (tid + it * 256) * 4;
            float4 v = *(const float4*)(Wv + e);
            *(__half2*)(Wv16 + e)     = __floats2half2_rn(v.x, v.y);
            *(__half2*)(Wv16 + e + 2) = __floats2half2_rn(v.z, v.w);
        }
    } else if (bid < 296) {
        float (*Wl)[68] = (float(*)[68])smem;
        const int t2 = bid - 280;
        const int which = t2 >> 3;               // 0 -> Wk/GW, 1 -> Wq/GQ
        const int sl = t2 & 7;
        const int i0 = sl * 64;
        const float* W = which ? Wq : Wk;
        float* Gout = GWQpart + (long long)(which * 8 + sl) * 4096;
#pragma unroll
        for (int it = 0; it < 4; it++) {
            int e = tid + it * 256;
            int cc = e >> 4, i4 = (e & 15) * 4;
            *(float4*)&Wl[cc][i4] = *(const float4*)(W + cc * 512 + i0 + i4);
        }
        __syncthreads();
        if (tid < 64) {
            float s = 0.f;
#pragma unroll
            for (int j = 0; j < 64; j++) s += Wl[tid][j];
            wsp[(which * 8 + sl) * 64 + tid] = s;
        }
        const int cr = tid >> 2, cg = (tid & 3) * 16;
        float p[16] = {};
        for (int k = 0; k < 64; k++) {
            float a = Wl[cr][k];
#pragma unroll
            for (int j = 0; j < 16; j++) p[j] += a * Wl[cg + j][k];
        }
#pragma unroll
        for (int j = 0; j < 16; j++)
            Gout[cr * 64 + cg + j] = p[j];
    } else {
        // WqT split fp16: WqT[i][c] = Wq[c][i], hi + residual lo
        float (*t)[65] = (float(*)[65])smem;
        const int i0 = (bid - 296) * 64;
        const int c = tid & 63, r4 = tid >> 6;
#pragma unroll
        for (int rr = r4; rr < 64; rr += 4)
            t[rr][c] = Wq[rr * 512 + i0 + c];
        __syncthreads();
#pragma unroll
        for (int rr = r4; rr < 64; rr += 4) {
            float x = t[c][rr];
            __half h = __float2half(x);
            WqT16h[(i0 + rr) * 64 + c] = h;
            WqT16l[(i0 + rr) * 64 + c] = __float2half(x - __half2float(h));
        }
    }
}

// ---------------------------------------------------------------------------
// gram_k (grid 512): MFMA Gram partials from embT16, d=0 pairs only.
// ---------------------------------------------------------------------------
__global__ __launch_bounds__(256)
void gram_k(const __half* __restrict__ embT16, float* __restrict__ Gpart)
{
    const int tid = threadIdx.x, bid = blockIdx.x;
    const int ks = bid >> 6, z6 = bid & 63;
    const int b = z6 >> 3, bp = z6 & 7;
    const int lane = tid & 63, w = tid >> 6, q = lane >> 4, l16 = lane & 15;

    const __half* Arow = embT16 + (long long)b * 131072 +
                         (long long)(w * 16 + l16) * 2048 + ks * 256 + q * 8;
    const __half* Bbase = embT16 + 1048576 + (long long)bp * 131072 +
                          (long long)l16 * 2048 + ks * 256 + q * 8;

    float4v acc[4];
#pragma unroll
    for (int nt = 0; nt < 4; nt++) acc[nt] = (float4v)0.f;

#pragma unroll
    for (int t0 = 0; t0 < 256; t0 += 32) {
        half8 af = *(const half8*)(Arow + t0);
        half8 bf[4];
#pragma unroll
        for (int nt = 0; nt < 4; nt++)
            bf[nt] = *(const half8*)(Bbase + nt * 32768 + t0);
#pragma unroll
        for (int nt = 0; nt < 4; nt++)
            acc[nt] = __builtin_amdgcn_mfma_f32_16x16x32_f16(af, bf[nt], acc[nt], 0, 0, 0);
    }

    float* Gz = Gpart + (long long)ks * 262144 + (long long)z6 * 4096;
#pragma unroll
    for (int nt = 0; nt < 4; nt++)
#pragma unroll
        for (int t = 0; t < 4; t++) {
            int m = w * 16 + q * 4 + t;
            Gz[m * 64 + nt * 16 + l16] = acc[nt][t];
        }
}

// ---------------------------------------------------------------------------
// stats2: reduce Gpart (d=0 base, transpose for d=1), write logical G as
// TRANSPOSED split-fp16 (GT[c'][c], hi+lo), reduce GW/GQ/wsum, analytic IN
// stats -> sums2. grid 128 pairs.
// ---------------------------------------------------------------------------
__global__ __launch_bounds__(256)
void stats2_k(const float* __restrict__ Gpart, const float* __restrict__ GWQpart,
              const float* __restrict__ wsp, __half* __restrict__ GT16h,
              __half* __restrict__ GT16l, float* __restrict__ sums2)
{
    __shared__ float Graw[64][68], Gs[64][68], GQs[64][68], GWs[64][68];
    __shared__ float wqsS[64], wksS[64];
    const int tid = threadIdx.x;
    const int z = blockIdx.x;
    const int d = z >> 6, b = (z >> 3) & 7, bp = z & 7;
    const int zm = d ? (bp * 8 + b) : (b * 8 + bp);

    for (int f = tid * 4; f < 4096; f += 1024) {
        float4 g = make_float4(0.f, 0.f, 0.f, 0.f);
        float4 gw = g, gq = g;
#pragma unroll
        for (int s = 0; s < 8; s++) {
            float4 p = *(const float4*)(Gpart + (long long)s * 262144 + (long long)zm * 4096 + f);
            g.x += p.x; g.y += p.y; g.z += p.z; g.w += p.w;
            float4 w1 = *(const float4*)(GWQpart + (long long)s * 4096 + f);
            gw.x += w1.x; gw.y += w1.y; gw.z += w1.z; gw.w += w1.w;
            float4 q1 = *(const float4*)(GWQpart + (long long)(8 + s) * 4096 + f);
            gq.x += q1.x; gq.y += q1.y; gq.z += q1.z; gq.w += q1.w;
        }
        int rr = f >> 6, cc = f & 63;
        *(float4*)&Graw[rr][cc] = g;
        *(float4*)&GWs[rr][cc] = gw;
        *(float4*)&GQs[rr][cc] = gq;
    }
    if (tid < 64) {
        float a = 0.f, bsum = 0.f;
#pragma unroll
        for (int s = 0; s < 8; s++) {
            bsum += wsp[s * 64 + tid];          // Wk sums
            a    += wsp[(8 + s) * 64 + tid];    // Wq sums
        }
        wqsS[tid] = a; wksS[tid] = bsum;
    }
    __syncthreads();
    // logical G (transpose for d=1)
    for (int e = tid; e < 4096; e += 256) {
        int rr = e >> 6, cc = e & 63;
        Gs[rr][cc] = d ? Graw[cc][rr] : Graw[rr][cc];
    }
    __syncthreads();
    // store G TRANSPOSED as split fp16: GT[c'][c] = Gs[c][c']
    for (int e = tid; e < 4096; e += 256) {
        int cp = e >> 6, c = e & 63;
        float g = Gs[c][cp];
        __half h = __float2half(g);
        GT16h[(long long)z * 4096 + e] = h;
        GT16l[(long long)z * 4096 + e] = __float2half(g - __half2float(h));
    }

    const int r = tid >> 2;
    const int c0 = (tid & 3) * 16;
    float p1[16] = {}, p2[16] = {};
    for (int k = 0; k < 64; k++) {
        float gq = GQs[r][k], g = Gs[r][k];
#pragma unroll
        for (int j = 0; j < 16; j++) {
            p1[j] += gq * Gs[k][c0 + j];
            p2[j] += g  * GWs[k][c0 + j];
        }
    }
    float s2 = 0.f;
#pragma unroll
    for (int j = 0; j < 16; j++) s2 += p1[j] * p2[j];
    float s1 = 0.f;
    const float wq = wqsS[r];
#pragma unroll
    for (int j = 0; j < 16; j++) s1 += wq * Gs[r][c0 + j] * wksS[c0 + j];

    const int lane = tid & 63, w = tid >> 6;
#pragma unroll
    for (int off = 32; off; off >>= 1) {
        s1 += __shfl_down(s1, off, 64);
        s2 += __shfl_down(s2, off, 64);
    }
    __shared__ float r1[4], r2[4];
    if (lane == 0) { r1[w] = s1; r2[w] = s2; }
    __syncthreads();
    if (tid == 0) {
        sums2[z * 2]     = r1[0] + r1[1] + r1[2] + r1[3];
        sums2[z * 2 + 1] = r2[0] + r2[1] + r2[2] + r2[3];
    }
}

// ---------------------------------------------------------------------------
// Fused E + MS, double-buffered LDS staging (T14 issue-early / write-late):
//   prologue: issue chunk-0 Wk/Wv loads -> regs; E-phase MFMA hides them;
//             write regs -> buf0; 1 barrier.
//   chunk c:  issue chunk-(c+1) loads -> regs; S-mfma/exp/M-mfma from
//             buf[cur] (load latency hidden under compute); write regs ->
//             buf[cur^1]; 1 barrier.
// Es/Pt rows stay wave-private (no barriers for E->S / exp->M).
// grid (128 z, 4 it), block 256. LDS 72 KB -> 2 blocks/CU.
// ---------------------------------------------------------------------------
__global__ __launch_bounds__(256)
void mfma_ms(const __half* __restrict__ WqT16h, const __half* __restrict__ WqT16l,
             const __half* __restrict__ GT16h, const __half* __restrict__ GT16l,
             const __half* __restrict__ WkT16, const __half* __restrict__ Wv16,
             const float* __restrict__ sums2, float* __restrict__ rsp,
             __half* __restrict__ Mt)
{
    __shared__ __half Es[128][72];
    __shared__ __half Wks[2][64][72];
    __shared__ __half Wvs[2][64][72];
    __shared__ __half Pt[128][72];   // reused as MtS[64][144] at the end

    const int tid = threadIdx.x;
    const int z = blockIdx.x;
    const int it = blockIdx.y;
    const int db = z >> 3, bp = z & 7;
    const int i0base = it * 128;

    const int lane = tid & 63, w = tid >> 6, q = lane >> 4, l16 = lane & 15;
    const float rv = rv_from(sums2, db);
    const int srow = tid >> 2, sc8 = (tid & 3) * 16;

    // ---- prologue: issue chunk-0 staging loads (hidden under E-phase) ----
    half8 gk0 = *(const half8*)(WkT16 + (long long)srow * 64 + sc8);
    half8 gk1 = *(const half8*)(WkT16 + (long long)srow * 64 + sc8 + 8);
    half8 gv0 = *(const half8*)(Wv16 + (long long)srow * 512 + sc8);
    half8 gv1 = *(const half8*)(Wv16 + (long long)srow * 512 + sc8 + 8);

    // ---- E-phase: Es rows [w*32, w*32+32) from WqT (split) x GT (split) ----
    {
        const __half* Wh = WqT16h + (long long)i0base * 64;
        const __half* Wl = WqT16l + (long long)i0base * 64;
        const __half* Gh = GT16h + (long long)z * 4096;
        const __half* Gl = GT16l + (long long)z * 4096;
        float4v eacc[2][4];
#pragma unroll
        for (int a = 0; a < 2; a++)
#pragma unroll
            for (int b2 = 0; b2 < 4; b2++) eacc[a][b2] = (float4v)0.f;
#pragma unroll
        for (int kc = 0; kc < 64; kc += 32) {
            half8 ah[2], al[2], bh[4], bl[4];
#pragma unroll
            for (int mt = 0; mt < 2; mt++) {
                const int i = w * 32 + mt * 16 + l16;
                ah[mt] = *(const half8*)(Wh + i * 64 + kc + q * 8);
                al[mt] = *(const half8*)(Wl + i * 64 + kc + q * 8);
            }
#pragma unroll
            for (int nt = 0; nt < 4; nt++) {
                const int cp = nt * 16 + l16;
                bh[nt] = *(const half8*)(Gh + cp * 64 + kc + q * 8);
                bl[nt] = *(const half8*)(Gl + cp * 64 + kc + q * 8);
            }
#pragma unroll
            for (int mt = 0; mt < 2; mt++)
#pragma unroll
                for (int nt = 0; nt < 4; nt++) {
                    eacc[mt][nt] = __builtin_amdgcn_mfma_f32_16x16x32_f16(ah[mt], bh[nt], eacc[mt][nt], 0, 0, 0);
                    eacc[mt][nt] = __builtin_amdgcn_mfma_f32_16x16x32_f16(ah[mt], bl[nt], eacc[mt][nt], 0, 0, 0);
                    eacc[mt][nt] = __builtin_amdgcn_mfma_f32_16x16x32_f16(al[mt], bh[nt], eacc[mt][nt], 0, 0, 0);
                }
        }
#pragma unroll
        for (int mt = 0; mt < 2; mt++)
#pragma unroll
            for (int nt = 0; nt < 4; nt++)
#pragma unroll
                for (int t = 0; t < 4; t++)
                    Es[w * 32 + mt * 16 + q * 4 + t][nt * 16 + l16] =
                        __float2half(eacc[mt][nt][t]);
    }
    // write staged chunk 0 (vmcnt wait fully hidden by E-phase)
    *(half8*)&Wks[0][srow][sc8]     = gk0;
    *(half8*)&Wks[0][srow][sc8 + 8] = gk1;
    *(half8*)&Wvs[0][srow][sc8]     = gv0;
    *(half8*)&Wvs[0][srow][sc8 + 8] = gv1;
    __syncthreads();

    float4v macc[2][4];   // [mt2: i-group][nt2: c'-group]
#pragma unroll
    for (int a = 0; a < 2; a++)
#pragma unroll
        for (int b2 = 0; b2 < 4; b2++) macc[a][b2] = (float4v)0.f;
    float rsacc[2] = {0.f, 0.f};

    int cur = 0;
    for (int c = 0; c < 8; c++) {
        const int ch0 = c * 64;
        // issue next chunk's staging loads early
        if (c < 7) {
            const int chn = ch0 + 64;
            gk0 = *(const half8*)(WkT16 + (long long)(chn + srow) * 64 + sc8);
            gk1 = *(const half8*)(WkT16 + (long long)(chn + srow) * 64 + sc8 + 8);
            gv0 = *(const half8*)(Wv16 + (long long)srow * 512 + chn + sc8);
            gv1 = *(const half8*)(Wv16 + (long long)srow * 512 + chn + sc8 + 8);
        }

        // S-mfma: m=ch (4 mt), n=i (2 nt per wave), k=c' (2 kc)
        float4v sacc[4][2];
#pragma unroll
        for (int a = 0; a < 4; a++)
#pragma unroll
            for (int b2 = 0; b2 < 2; b2++) sacc[a][b2] = (float4v)0.f;
#pragma unroll
        for (int kc = 0; kc < 64; kc += 32) {
            half8 af[4], bf[2];
#pragma unroll
            for (int mt = 0; mt < 4; mt++)
                af[mt] = *(const half8*)&Wks[cur][mt * 16 + l16][kc + q * 8];
#pragma unroll
            for (int nt = 0; nt < 2; nt++)
                bf[nt] = *(const half8*)&Es[w * 32 + nt * 16 + l16][kc + q * 8];
#pragma unroll
            for (int mt = 0; mt < 4; mt++)
#pragma unroll
                for (int nt = 0; nt < 2; nt++)
                    sacc[mt][nt] = __builtin_amdgcn_mfma_f32_16x16x32_f16(af[mt], bf[nt], sacc[mt][nt], 0, 0, 0);
        }

        // exp -> Pt[i][ch] (wave-private rows) + rs accum
#pragma unroll
        for (int nt = 0; nt < 2; nt++) {
            const int i = w * 32 + nt * 16 + l16;
#pragma unroll
            for (int mt = 0; mt < 4; mt++) {
                float e0 = __expf(rv * sacc[mt][nt][0]);
                float e1 = __expf(rv * sacc[mt][nt][1]);
                float e2 = __expf(rv * sacc[mt][nt][2]);
                float e3 = __expf(rv * sacc[mt][nt][3]);
                rsacc[nt] += e0 + e1 + e2 + e3;
                const int ch = mt * 16 + q * 4;
                *(__half2*)&Pt[i][ch]     = __floats2half2_rn(e0, e1);
                *(__half2*)&Pt[i][ch + 2] = __floats2half2_rn(e2, e3);
            }
        }
        // No barrier: M-phase reads only this wave's Pt rows.

        // M-mfma: m=i (2 mt2), n=c' (4 nt2), k=ch (2 kc)
#pragma unroll
        for (int kc = 0; kc < 64; kc += 32) {
            half8 af2[2], bf2[4];
#pragma unroll
            for (int mt2 = 0; mt2 < 2; mt2++)
                af2[mt2] = *(const half8*)&Pt[w * 32 + mt2 * 16 + l16][kc + q * 8];
#pragma unroll
            for (int nt2 = 0; nt2 < 4; nt2++)
                bf2[nt2] = *(const half8*)&Wvs[cur][nt2 * 16 + l16][kc + q * 8];
#pragma unroll
            for (int mt2 = 0; mt2 < 2; mt2++)
#pragma unroll
                for (int nt2 = 0; nt2 < 4; nt2++)
                    macc[mt2][nt2] = __builtin_amdgcn_mfma_f32_16x16x32_f16(af2[mt2], bf2[nt2], macc[mt2][nt2], 0, 0, 0);
        }

        // write-late: staged regs -> other buffer (vmcnt hidden by S/exp/M)
        if (c < 7) {
            *(half8*)&Wks[cur ^ 1][srow][sc8]     = gk0;
            *(half8*)&Wks[cur ^ 1][srow][sc8 + 8] = gk1;
            *(half8*)&Wvs[cur ^ 1][srow][sc8]     = gv0;
            *(half8*)&Wvs[cur ^ 1][srow][sc8 + 8] = gv1;
        }
        __syncthreads();
        cur ^= 1;
    }

    // rs partials: reduce over q (lane bits 4,5), store per (i, bp)
#pragma unroll
    for (int nt = 0; nt < 2; nt++) {
        float p = rsacc[nt];
        p += __shfl_xor(p, 16, 64);
        p += __shfl_xor(p, 32, 64);
        if (q == 0)
            rsp[(long long)(db * 512 + i0base + w * 32 + nt * 16 + l16) * 8 + bp] = p;
    }

    // Mt store: macc -> MtS[c'][i] (LDS) -> coalesced global [c'][i0base..+128]
    // (the loop's final __syncthreads already ordered all waves past Pt use)
    __half (*MtS)[144] = (__half(*)[144])&Pt[0][0];
    const float sc = 1.f / 4096.f;
#pragma unroll
    for (int mt2 = 0; mt2 < 2; mt2++)
#pragma unroll
        for (int nt2 = 0; nt2 < 4; nt2++) {
            const int cp = nt2 * 16 + l16;
            const int il = w * 32 + mt2 * 16 + q * 4;
#pragma unroll
            for (int t = 0; t < 4; t++)
                MtS[cp][il + t] = __float2half(macc[mt2][nt2][t] * sc);
        }
    __syncthreads();
    __half* Mz = Mt + (long long)z * 32768;
    {
        const int row = tid >> 2, seg = (tid & 3) * 32;
#pragma unroll
        for (int j = 0; j < 4; j++)
            *(half8*)(Mz + (long long)row * 512 + i0base + seg + j * 8) =
                *(const half8*)&MtS[row][seg + j * 8];
    }
}

// ---------------------------------------------------------------------------
// N gemm: NT[db][o][bp*64+c'] = sum_i Mt[z][c'][i]*(4096/rs[db][i])*Wo16[o][i]
// m=c', n=o (1 nt/wave), K=512. grid 128 (db*8+bp), block 256.
// ---------------------------------------------------------------------------
__global__ __launch_bounds__(256)
void mfma_n(const __half* __restrict__ Mt, const __half* __restrict__ Wo16,
            const float* __restrict__ rsp, __half* __restrict__ NT)
{
    __shared__ __half Mts[64][72];
    __shared__ __half Wos[64][72];
    __shared__ float invrS[64];
    const int tid = threadIdx.x;
    const int db = blockIdx.x >> 3, bp = blockIdx.x & 7;
    const __half* Mz = Mt + (long long)(db * 8 + bp) * 32768;
    const int lane = tid & 63, w = tid >> 6, q = lane >> 4, l16 = lane & 15;

    float4v acc[4];
#pragma unroll
    for (int mt = 0; mt < 4; mt++) acc[mt] = (float4v)0.f;

    const int srow = tid >> 2, sc8 = (tid & 3) * 16;

    for (int i0 = 0; i0 < 512; i0 += 64) {
        __syncthreads();
        if (tid < 64) {
            const float* rp = rsp + (long long)(db * 512 + i0 + tid) * 8;
            float4 a = *(const float4*)rp;
            float4 b = *(const float4*)(rp + 4);
            invrS[tid] = 4096.0f / (a.x + a.y + a.z + a.w + b.x + b.y + b.z + b.w);
        }
        __syncthreads();
#pragma unroll
        for (int h = 0; h < 2; h++) {
            half8 v = *(const half8*)(Mz + (long long)srow * 512 + i0 + sc8 + h * 8);
            half8 o;
#pragma unroll
            for (int j = 0; j < 8; j++)
                o[j] = (_Float16)((float)v[j] * invrS[sc8 + h * 8 + j]);
            *(half8*)&Mts[srow][sc8 + h * 8] = o;
            *(half8*)&Wos[srow][sc8 + h * 8] =
                *(const half8*)(Wo16 + (long long)srow * 512 + i0 + sc8 + h * 8);
        }
        __syncthreads();
#pragma unroll
        for (int kc = 0; kc < 64; kc += 32) {
            half8 af[4];
#pragma unroll
            for (int mt = 0; mt < 4; mt++)
                af[mt] = *(const half8*)&Mts[mt * 16 + l16][kc + q * 8];
            half8 bf = *(const half8*)&Wos[w * 16 + l16][kc + q * 8];
#pragma unroll
            for (int mt = 0; mt < 4; mt++)
                acc[mt] = __builtin_amdgcn_mfma_f32_16x16x32_f16(af[mt], bf, acc[mt], 0, 0, 0);
        }
    }

    __half* Nz = NT + (long long)db * 32768;
    const int o = w * 16 + l16;
#pragma unroll
    for (int mt = 0; mt < 4; mt++) {
        const int k = bp * 64 + mt * 16 + q * 4;
        *(__half2*)(Nz + (long long)o * 512 + k)     = __floats2half2_rn(acc[mt][0], acc[mt][1]);
        *(__half2*)(Nz + (long long)o * 512 + k + 2) = __floats2half2_rn(acc[mt][2], acc[mt][3]);
    }
}

// ---------------------------------------------------------------------------
// MFMA out:  out[db][n][o] = sum_{bp,c} emb16_kv[bp][n][c] * NT[db][o][bp*64+c]
// ---------------------------------------------------------------------------
__global__ __launch_bounds__(256)
void mfma_out(const __half* __restrict__ emb16, const __half* __restrict__ NT,
              float* __restrict__ out)
{
    const int tid = threadIdx.x;
    const int db = blockIdx.y;
    const int d = db >> 3;
    const int n0 = blockIdx.x * 128;
    const __half* Xb = emb16 + (long long)(1 - d) * 1048576;
    const __half* Bz = NT + (long long)db * 32768;

    const int lane = tid & 63, w = tid >> 6, q = lane >> 4, l16 = lane & 15;

    float4v acc[2][4];
#pragma unroll
    for (int a = 0; a < 2; a++)
#pragma unroll
        for (int b = 0; b < 4; b++) acc[a][b] = (float4v)0.f;

    for (int bp = 0; bp < 8; bp++) {
        const __half* src = Xb + (long long)bp * 131072 + (long long)n0 * 64;
#pragma unroll
        for (int kc = 0; kc < 64; kc += 32) {
            half8 af[2], bf[4];
#pragma unroll
            for (int mt = 0; mt < 2; mt++)
                af[mt] = *(const half8*)(src + (long long)(w * 32 + mt * 16 + l16) * 64 + kc + q * 8);
#pragma unroll
            for (int ot = 0; ot < 4; ot++)
                bf[ot] = *(const half8*)(Bz + (long long)(ot * 16 + l16) * 512 + bp * 64 + kc + q * 8);
#pragma unroll
            for (int mt = 0; mt < 2; mt++)
#pragma unroll
                for (int ot = 0; ot < 4; ot++)
                    acc[mt][ot] = __builtin_amdgcn_mfma_f32_16x16x32_f16(af[mt], bf[ot], acc[mt][ot], 0, 0, 0);
        }
    }

    float* Od = out + (long long)db * 131072;
#pragma unroll
    for (int mt = 0; mt < 2; mt++)
#pragma unroll
        for (int ot = 0; ot < 4; ot++)
#pragma unroll
            for (int t = 0; t < 4; t++) {
                int n = n0 + w * 32 + mt * 16 + q * 4 + t;
                Od[(long long)n * 64 + ot * 16 + l16] = acc[mt][ot][t];
            }
}

// ---------------------------------------------------------------------------
// Workspace (float offsets, no zero-init anywhere):
//   Gpart @0: 2097152
//   GWQpart @2097152: 65536 | wsp @2162688: 1024 | sums2 @2163712: 256
//   GT16h (half) @2163968 | GT16l @2426112
//   rsp @2688256: 65536
//   WkT16 @2753792 | Wv16 @2770176 | Wo16 @2786560
//   WqT16h @2802944 | WqT16l @2819328
//   Mt @2835712 | NT @4932864
//   emb16 @5195008 | embT16 @6243584 -> 7292160
// ---------------------------------------------------------------------------
extern "C" void kernel_launch(void* const* d_in, const int* in_sizes, int n_in,
                              void* d_out, int out_size, void* d_ws, size_t ws_size,
                              hipStream_t stream)
{
    const float* emb = (const float*)d_in[0];
    const float* Wq  = (const float*)d_in[1];
    const float* Wk  = (const float*)d_in[2];
    const float* Wv  = (const float*)d_in[3];
    const float* Wo  = (const float*)d_in[4];
    float* out = (float*)d_out;
    float* ws  = (float*)d_ws;

    float* Gpart   = ws;
    float* GWQpart = ws + 2097152;
    float* wsp     = ws + 2162688;
    float* sums2   = ws + 2163712;
    __half* GT16h  = (__half*)(ws + 2163968);
    __half* GT16l  = (__half*)(ws + 2426112);
    float* rsp     = ws + 2688256;
    __half* WkT16  = (__half*)(ws + 2753792);
    __half* Wv16   = (__half*)(ws + 2770176);
    __half* Wo16   = (__half*)(ws + 2786560);
    __half* WqT16h = (__half*)(ws + 2802944);
    __half* WqT16l = (__half*)(ws + 2819328);
    __half* Mt     = (__half*)(ws + 2835712);
    __half* NT     = (__half*)(ws + 4932864);
    __half* emb16  = (__half*)(ws + 5195008);
    __half* embT16 = (__half*)(ws + 6243584);

    // one-shot fp16 conversions (emb both layouts) + weight prep + GW/GQ/wsum
    convT_k<<<304, 256, 0, stream>>>(emb, Wq, Wk, Wv, Wo, emb16, embT16,
                                     WkT16, Wo16, Wv16, GWQpart, wsp,
                                     WqT16h, WqT16l);

    // Gram partials (d=0 only), pure global-fragment MFMA
    gram_k<<<512, 256, 0, stream>>>(embT16, Gpart);

    // reduce partials (+transpose for d=1) + split-fp16 G^T + analytic stats
    stats2_k<<<128, 256, 0, stream>>>(Gpart, GWQpart, wsp, GT16h, GT16l, sums2);

    // fused E + S + exp + V-contraction, double-buffered staging
    mfma_ms<<<dim3(128, 4), 256, 0, stream>>>(WqT16h, WqT16l, GT16h, GT16l,
                                              WkT16, Wv16, sums2, rsp, Mt);

    // NT[db][o][k] = sum_i (Mt/rs) * Wo   (softmax normalization folded here)
    mfma_n<<<128, 256, 0, stream>>>(Mt, Wo16, rsp, NT);

    // out[db][n][o] = sum_k emb16_kv * NT   (MFMA f16, fp32 out)
    mfma_out<<<dim3(16, 16), 256, 0, stream>>>(emb16, NT, out);
}